// Round 4
// baseline (424.428 us; speedup 1.0000x reference)
//
#include <hip/hip_runtime.h>
#include <stdint.h>
#include <stddef.h>

typedef unsigned short u16;
typedef __bf16 bf16x8 __attribute__((ext_vector_type(8)));
typedef float floatx4 __attribute__((ext_vector_type(4)));

#define B_  4
#define S_  2048
#define D_  1024
#define H_  16
#define DH_ 64

__device__ __forceinline__ float b2f(u16 u) {
  union { unsigned u; float f; } c; c.u = ((unsigned)u) << 16; return c.f;
}
__device__ __forceinline__ u16 f2b(float f) {
  union { float f; unsigned u; } c; c.f = f;
  unsigned u = c.u;
  u += 0x7fffu + ((u >> 16) & 1u);   // round-to-nearest-even
  return (u16)(u >> 16);
}

// async global->LDS, 16B per lane. LDS dest: wave-uniform base + lane*16.
__device__ __forceinline__ void gld_lds16(const u16* g, u16* l) {
  __builtin_amdgcn_global_load_lds(
      (const __attribute__((address_space(1))) unsigned int*)g,
      (__attribute__((address_space(3))) unsigned int*)l, 16, 0, 0);
}

// pack two f32 -> one u32 of 2 bf16 (no builtin on gfx950; T12 recipe)
__device__ __forceinline__ unsigned cvtpk(float lo, float hi) {
  unsigned r;
  asm("v_cvt_pk_bf16_f32 %0, %1, %2" : "=v"(r) : "v"(lo), "v"(hi));
  return r;
}

// permlane swaps: diagonal transpose of (reg-index, lane-bit) 2x2
#define PL32(a, b) asm("v_permlane32_swap_b32 %0, %1" : "+v"(a), "+v"(b))
#define PL16(a, b) asm("v_permlane16_swap_b32 %0, %1" : "+v"(a), "+v"(b))

union B8 { unsigned u[4]; bf16x8 v; };

// ---------------------------------------------------------------------------
// Kernel 0: fp32 -> bf16 convert (for weights). n must be a multiple of 4.
// ---------------------------------------------------------------------------
__global__ __launch_bounds__(256) void cvt_f32_bf16(
    const float* __restrict__ src, u16* __restrict__ dst, int n)
{
  int i = (blockIdx.x * 256 + threadIdx.x) * 4;
  if (i >= n) return;
  float4 v = *(const float4*)(src + i);
  u16 o[4] __attribute__((aligned(8)));
  o[0] = f2b(v.x); o[1] = f2b(v.y); o[2] = f2b(v.z); o[3] = f2b(v.w);
  *(uint2*)(dst + i) = *(uint2*)o;
}

// ---------------------------------------------------------------------------
// Kernel 1: LayerNorm + pos_emb add. fp32 in, bf16 out. One block per row.
// ---------------------------------------------------------------------------
__global__ __launch_bounds__(256) void ln_pos_kernel(
    const float* __restrict__ x, const float* __restrict__ pos,
    const float* __restrict__ gamma, const float* __restrict__ beta,
    u16* __restrict__ xp)
{
  const int row = blockIdx.x;
  const int s = row & (S_ - 1);
  const int t = threadIdx.x;
  const int lane = t & 63, w = t >> 6;

  float4 xv = *(const float4*)(x + (size_t)row * D_ + t * 4);
  float f[4] = {xv.x, xv.y, xv.z, xv.w};
  float sum = f[0] + f[1] + f[2] + f[3];
  float sq  = f[0]*f[0] + f[1]*f[1] + f[2]*f[2] + f[3]*f[3];
#pragma unroll
  for (int m = 1; m < 64; m <<= 1) {
    sum += __shfl_xor(sum, m);
    sq  += __shfl_xor(sq, m);
  }
  __shared__ float red[8];
  if (lane == 0) { red[w] = sum; red[4 + w] = sq; }
  __syncthreads();
  sum = red[0] + red[1] + red[2] + red[3];
  sq  = red[4] + red[5] + red[6] + red[7];
  const float mu = sum * (1.f / D_);
  const float rstd = rsqrtf(fmaxf(sq * (1.f / D_) - mu * mu, 0.f) + 1e-5f);

  float4 gv = *(const float4*)(gamma + t * 4);
  float4 bv = *(const float4*)(beta + t * 4);
  float4 pv = *(const float4*)(pos + (size_t)s * D_ + t * 4);
  float g[4] = {gv.x, gv.y, gv.z, gv.w};
  float bb[4] = {bv.x, bv.y, bv.z, bv.w};
  float pp[4] = {pv.x, pv.y, pv.z, pv.w};
  u16 ov[4] __attribute__((aligned(8)));
#pragma unroll
  for (int i = 0; i < 4; ++i)
    ov[i] = f2b((f[i] - mu) * rstd * g[i] + bb[i] + pp[i]);
  *(uint2*)(xp + (size_t)row * D_ + t * 4) = *(uint2*)ov;
}

// ---------------------------------------------------------------------------
// Kernel 2: C[M,N] = A[M,K] @ B[N,K]^T (+bias[N]) (+res[M,N]); bf16 A/B,
// fp32 acc; C stored bf16 (internal) or fp32 (final). A row-stride lda,
// C/res row-stride ldc. 128x128 tile, BK=32, 4 waves, wave = 64x64.
// LDS chunk-rotation swizzle p=(ch+(row>>1))&3 -> conflict-free frag reads.
// No __restrict__ on A/res/C: kernel 4 runs in-place (res==C, elementwise).
// ---------------------------------------------------------------------------
template<int HAS_BIAS, int HAS_RES, int OUT_F32>
__global__ __launch_bounds__(256) void gemm_bt(
    const u16* A, const u16* __restrict__ Bm,
    const float* __restrict__ bias, const u16* res,
    void* Cv, int M, int N, int K, int lda, int ldc)
{
  __shared__ u16 As[128 * 32];
  __shared__ u16 Bs[128 * 32];
  const int tid = threadIdx.x;
  const int lane = tid & 63, w = tid >> 6;
  const int quad = lane >> 4, l4 = lane & 15;
  const int wm = (w >> 1) * 64, wn = (w & 1) * 64;
  const int m0 = blockIdx.y * 128, n0 = blockIdx.x * 128;

  const u16* Ag = A + (size_t)m0 * lda;
  const u16* Bg = Bm + (size_t)n0 * K;

  const int s0 = tid, s1 = tid + 256;
  const int r0 = s0 >> 2, c0 = ((s0 & 3) - (r0 >> 1)) & 3;
  const int r1 = s1 >> 2, c1 = ((s1 & 3) - (r1 >> 1)) & 3;
  const int pA = (quad + (l4 >> 1)) & 3;   // frag-read swizzled chunk position

  floatx4 acc[4][4] = {};

  for (int k0 = 0; k0 < K; k0 += 32) {
    __syncthreads();
    gld_lds16(Ag + (size_t)r0 * lda + k0 + c0 * 8, &As[s0 * 8]);
    gld_lds16(Ag + (size_t)r1 * lda + k0 + c1 * 8, &As[s1 * 8]);
    gld_lds16(Bg + (size_t)r0 * K + k0 + c0 * 8, &Bs[s0 * 8]);
    gld_lds16(Bg + (size_t)r1 * K + k0 + c1 * 8, &Bs[s1 * 8]);
    __syncthreads();
    bf16x8 af[4], bfr[4];
#pragma unroll
    for (int i = 0; i < 4; ++i)
      af[i] = *(const bf16x8*)&As[(wm + i * 16 + l4) * 32 + pA * 8];
#pragma unroll
    for (int j = 0; j < 4; ++j)
      bfr[j] = *(const bf16x8*)&Bs[(wn + j * 16 + l4) * 32 + pA * 8];
#pragma unroll
    for (int i = 0; i < 4; ++i)
#pragma unroll
      for (int j = 0; j < 4; ++j)
        acc[i][j] = __builtin_amdgcn_mfma_f32_16x16x32_bf16(af[i], bfr[j], acc[i][j], 0, 0, 0);
  }

#pragma unroll
  for (int i = 0; i < 4; ++i) {
#pragma unroll
    for (int j = 0; j < 4; ++j) {
      const int col = n0 + wn + j * 16 + l4;
      float bvv = 0.f;
      if (HAS_BIAS) bvv = bias[col];
#pragma unroll
      for (int r = 0; r < 4; ++r) {
        const int row = m0 + wm + i * 16 + quad * 4 + r;
        float v = acc[i][j][r] + bvv;
        if (HAS_RES) v += b2f(res[(size_t)row * ldc + col]);
        v = fminf(fmaxf(v, -60000.f), 60000.f);  // diagnostic fingerprint; no-op on valid data
        if (OUT_F32) ((float*)Cv)[(size_t)row * ldc + col] = v;
        else         ((u16*)Cv)[(size_t)row * ldc + col] = f2b(v);
      }
    }
  }
}

// ---------------------------------------------------------------------------
// Kernel 3: attention, double-buffered 2-phase pipeline. One block = (b, h,
// 64 Q rows), 4 waves, wave owns 16 Q rows. KV tile = 64 rows (32 iters).
//   - Per iter: ISSUE next tile's loads (K via global_load_lds, V to regs),
//     THEN compute on current buffers, THEN write Vt[next] from regs, THEN
//     one barrier (its vmcnt drain lands after a full compute phase of
//     hiding). All staging primitives are the R2/baseline-proven ones —
//     tr_read retired (falsified R1+R3, identical deterministic absmax).
//   - SWAPPED QK^T (S^T in regs), softmax fully in-register (verified R2).
//   - P -> PV A-frag in-register: cvtpk + permlane32/16_swap (verified R2).
//   - LDS 34 KB -> 4 blocks/CU at __launch_bounds__(256,4).
// No max-subtraction (scores clamped at 30, fp32-safe), single divide at end.
// Output overwrites the Q-slot of qkv (Q read to registers up front).
// ---------------------------------------------------------------------------
__global__ __launch_bounds__(256, 4) void attn_kernel(
    u16* qkv, const float* __restrict__ mask)
{
  __shared__ u16 Ks[2][64 * 64];    // 2 x 8 KB, chunk-rotation swizzle
  __shared__ u16 Vt[2][64 * 72];    // 2 x 9 KB, V transposed, +8 pad

  const int tid = threadIdx.x;
  const int lane = tid & 63, w = tid >> 6;
  const int quad = lane >> 4, l4 = lane & 15;
  const int qb = blockIdx.x;           // 0..31
  const int bh = blockIdx.y;           // 0..63
  const int b = bh >> 4, h = bh & 15;
  const int q0 = qb * 64;

  const size_t rstr = 3 * D_;
  u16* qbase = qkv + (size_t)b * S_ * rstr + h * DH_;

  // Q fragments straight to registers (B-operand: row=l4, k-chunk=quad).
  bf16x8 qfrag[2];
  {
    const u16* qp = qbase + (size_t)(q0 + w * 16 + l4) * rstr + quad * 8;
    qfrag[0] = *(const bf16x8*)(qp);
    qfrag[1] = *(const bf16x8*)(qp + 32);
  }

  const u16* kbase0 = qkv + (size_t)b * S_ * rstr + D_ + h * DH_;
  const u16* vbase0 = kbase0 + D_;
  const int vs = tid & 63, vd0 = (tid >> 6) * 16;   // V reg-load: row vs, d block

  floatx4 acc_o[4] = {};
  float l_run = 0.f;
  u16 vreg[16] __attribute__((aligned(16)));        // V[vs][vd0..vd0+16) of next tile

  // --- prologue: tile 0 ---
  {
    const u16* kb = kbase0;
#pragma unroll
    for (int t = 0; t < 2; ++t) {      // K: 64 rows x 8 chunks = 512, 2/thread
      int sidx = tid + t * 256;
      int rr = sidx >> 3, ch = ((sidx & 7) - rr) & 7;
      gld_lds16(kb + (size_t)rr * rstr + ch * 8, &Ks[0][sidx * 8]);
    }
    const u16* vp = vbase0 + (size_t)vs * rstr + vd0;
    *(uint4*)(vreg)     = *(const uint4*)(vp);
    *(uint4*)(vreg + 8) = *(const uint4*)(vp + 8);
  }
  __syncthreads();                     // drains vmcnt: K0 in LDS, V0 in regs
#pragma unroll
  for (int d = 0; d < 16; ++d) Vt[0][(vd0 + d) * 72 + vs] = vreg[d];
  __syncthreads();                     // Vt0 visible to all waves

  int cur = 0;
  for (int j = 0; j < 32; ++j) {
    // phase 1: issue next tile's loads (V regs first so its vmcnt wait
    // doesn't drain the K gld_lds queue)
    if (j < 31) {
      const u16* vp = vbase0 + ((size_t)(j + 1) * 64 + vs) * rstr + vd0;
      *(uint4*)(vreg)     = *(const uint4*)(vp);
      *(uint4*)(vreg + 8) = *(const uint4*)(vp + 8);
      const u16* kb = kbase0 + (size_t)(j + 1) * 64 * rstr;
#pragma unroll
      for (int t = 0; t < 2; ++t) {
        int sidx = tid + t * 256;
        int rr = sidx >> 3, ch = ((sidx & 7) - rr) & 7;
        gld_lds16(kb + (size_t)rr * rstr + ch * 8, &Ks[cur ^ 1][sidx * 8]);
      }
    }

    // phase 2: S^T tiles on Ks[cur]: accs[tj][r] = S[k=tj*16+quad*4+r][q=w*16+l4]
    floatx4 accs[4] = {};
#pragma unroll
    for (int kc = 0; kc < 2; ++kc)
#pragma unroll
      for (int tj = 0; tj < 4; ++tj) {
        const int rk = tj * 16 + l4;
        bf16x8 kf = *(const bf16x8*)&Ks[cur][rk * 64 + (((kc * 4 + quad) + rk) & 7) * 8];
        accs[tj] = __builtin_amdgcn_mfma_f32_16x16x32_bf16(kf, qfrag[kc], accs[tj], 0, 0, 0);
      }

    // in-register softmax (no max-sub) + bf16 pack
    const float* mrow = mask + (size_t)b * S_ + j * 64 + quad * 4;
    float rsum = 0.f;
    unsigned pk[4][2];
#pragma unroll
    for (int tj = 0; tj < 4; ++tj) {
      float4 mv = *(const float4*)(mrow + tj * 16);
      float p0 = __expf(fminf(fmaf(accs[tj][0], 0.125f, 1.0f - mv.x), 30.f));
      float p1 = __expf(fminf(fmaf(accs[tj][1], 0.125f, 1.0f - mv.y), 30.f));
      float p2 = __expf(fminf(fmaf(accs[tj][2], 0.125f, 1.0f - mv.z), 30.f));
      float p3 = __expf(fminf(fmaf(accs[tj][3], 0.125f, 1.0f - mv.w), 30.f));
      rsum += (p0 + p1) + (p2 + p3);
      pk[tj][0] = cvtpk(p0, p1);
      pk[tj][1] = cvtpk(p2, p3);
    }
    rsum += __shfl_xor(rsum, 16);   // reduce across quads (q-row = l4)
    rsum += __shfl_xor(rsum, 32);
    l_run += rsum;

    // O += P V on Vt[cur]: per kc, in-register P exchange + 4 Vt reads
#pragma unroll
    for (int kc = 0; kc < 2; ++kc) {
      unsigned x0 = pk[2 * kc][0], x1 = pk[2 * kc + 1][0];
      unsigned y0 = pk[2 * kc][1], y1 = pk[2 * kc + 1][1];
      PL32(x0, x1); PL32(y0, y1);   // reg-pair bit <-> lane-bit5
      PL16(x0, x1); PL16(y0, y1);   // reg-pair bit <-> lane-bit4
      B8 pa; pa.u[0] = x0; pa.u[1] = y0; pa.u[2] = x1; pa.u[3] = y1;
      __builtin_amdgcn_s_setprio(1);
#pragma unroll
      for (int tn = 0; tn < 4; ++tn) {
        bf16x8 bfr = *(const bf16x8*)&Vt[cur][(tn * 16 + l4) * 72 + kc * 32 + quad * 8];
        acc_o[tn] = __builtin_amdgcn_mfma_f32_16x16x32_bf16(pa.v, bfr, acc_o[tn], 0, 0, 0);
      }
      __builtin_amdgcn_s_setprio(0);
    }

    // phase 3: write next tile's Vt (prev-iter barrier guarantees Vt[cur^1]
    // is no longer being read by any wave; compiler inserts the vmcnt wait
    // for vreg here — after a full compute phase of hiding)
    if (j < 31) {
#pragma unroll
      for (int d = 0; d < 16; ++d) Vt[cur ^ 1][(vd0 + d) * 72 + vs] = vreg[d];
    }

    __syncthreads();   // drains K gld_lds (issued pre-compute) + Vt writes
    cur ^= 1;
  }

  // epilogue: O row (quad*4+r)'s rowsum lives at lane l4 = quad*4+r
  float inv[4];
#pragma unroll
  for (int r = 0; r < 4; ++r) inv[r] = 1.0f / __shfl(l_run, quad * 4 + r);
#pragma unroll
  for (int tn = 0; tn < 4; ++tn) {
#pragma unroll
    for (int r = 0; r < 4; ++r) {
      const int row = q0 + w * 16 + quad * 4 + r;
      const int col = h * DH_ + tn * 16 + l4;
      qkv[((size_t)b * S_ + row) * rstr + col] = f2b(acc_o[tn][r] * inv[r]);
    }
  }
}

// ---------------------------------------------------------------------------
extern "C" void kernel_launch(void* const* d_in, const int* in_sizes, int n_in,
                              void* d_out, int out_size, void* d_ws, size_t ws_size,
                              hipStream_t stream) {
  const float* x    = (const float*)d_in[0];
  const float* mask = (const float*)d_in[1];
  const float* pos  = (const float*)d_in[2];
  const float* gam  = (const float*)d_in[3];
  const float* bet  = (const float*)d_in[4];
  const float* wqkv = (const float*)d_in[5];
  const float* bqkv = (const float*)d_in[6];
  const float* wo   = (const float*)d_in[7];
  const float* bo   = (const float*)d_in[8];
  const float* wt   = (const float*)d_in[9];
  const float* bt   = (const float*)d_in[10];
  float* out = (float*)d_out;

  // workspace: exactly 64 MiB
  char* ws = (char*)d_ws;
  u16* qkvb = (u16*)(ws);                        // 8192 x 3072 bf16 = 50.33 MB
  u16* xp   = (u16*)(ws + (size_t)50331648);     // 8192 x 1024 bf16 = 16.78 MB

  // weight scratch in d_out (dead until kernel 5; 8.4 MB of 33.5 MB):
  u16* wqkv_b = (u16*)d_out;                              // 3072x1024 bf16
  u16* wo_b   = (u16*)((char*)d_out + (size_t)6291456);   // 1024x1024 bf16
  // wt converted into qkvb region after kernel 4 (qkvb dead by then)
  u16* wt_b   = qkvb;

  const int nqkv = 3 * D_ * D_;   // 3,145,728
  const int nd   = D_ * D_;       // 1,048,576

  // 0. convert weights used before kernel 5
  cvt_f32_bf16<<<nqkv / 1024, 256, 0, stream>>>(wqkv, wqkv_b, nqkv);
  cvt_f32_bf16<<<nd   / 1024, 256, 0, stream>>>(wo,   wo_b,   nd);
  // 1. layernorm + pos emb -> xp (bf16)
  ln_pos_kernel<<<B_ * S_, 256, 0, stream>>>(x, pos, gam, bet, xp);
  // 2. qkv = xp @ Wqkv^T + b   [8192,3072] bf16
  gemm_bt<1, 0, 0><<<dim3(3 * D_ / 128, B_ * S_ / 128), 256, 0, stream>>>(
      xp, wqkv_b, bqkv, nullptr, qkvb, B_ * S_, 3 * D_, D_, D_, 3 * D_);
  // 3. attention; output overwrites the Q-slot of qkvb (stride 3072)
  attn_kernel<<<dim3(S_ / 64, B_ * H_), 256, 0, stream>>>(qkvb, mask);
  // 4. xp = attn_out @ Wo^T + bo + xp   (A = Q-slot of qkvb, lda=3072; in-place)
  gemm_bt<1, 1, 0><<<dim3(D_ / 128, B_ * S_ / 128), 256, 0, stream>>>(
      qkvb, wo_b, bo, xp, xp, B_ * S_, D_, D_, 3 * D_, D_);
  // 4b. convert Wt into (now dead) qkvb region
  cvt_f32_bf16<<<nd / 1024, 256, 0, stream>>>(wt, wt_b, nd);
  // 5. out = xp @ Wt^T + bt  -> fp32 d_out
  gemm_bt<1, 0, 1><<<dim3(D_ / 128, B_ * S_ / 128), 256, 0, stream>>>(
      xp, wt_b, bt, nullptr, out, B_ * S_, D_, D_, D_, D_);
}

// Round 5
// 409.948 us; speedup vs baseline: 1.0353x; 1.0353x over previous
//
#include <hip/hip_runtime.h>
#include <stdint.h>
#include <stddef.h>

typedef unsigned short u16;
typedef __bf16 bf16x8 __attribute__((ext_vector_type(8)));
typedef float floatx4 __attribute__((ext_vector_type(4)));

#define B_  4
#define S_  2048
#define D_  1024
#define H_  16
#define DH_ 64

__device__ __forceinline__ float b2f(u16 u) {
  union { unsigned u; float f; } c; c.u = ((unsigned)u) << 16; return c.f;
}
__device__ __forceinline__ u16 f2b(float f) {
  union { float f; unsigned u; } c; c.f = f;
  unsigned u = c.u;
  u += 0x7fffu + ((u >> 16) & 1u);   // round-to-nearest-even
  return (u16)(u >> 16);
}

// async global->LDS, 16B per lane. LDS dest: wave-uniform base + lane*16.
__device__ __forceinline__ void gld_lds16(const u16* g, u16* l) {
  __builtin_amdgcn_global_load_lds(
      (const __attribute__((address_space(1))) unsigned int*)g,
      (__attribute__((address_space(3))) unsigned int*)l, 16, 0, 0);
}

// pack two f32 -> one u32 of 2 bf16 (no builtin on gfx950; T12 recipe)
__device__ __forceinline__ unsigned cvtpk(float lo, float hi) {
  unsigned r;
  asm("v_cvt_pk_bf16_f32 %0, %1, %2" : "=v"(r) : "v"(lo), "v"(hi));
  return r;
}

// permlane swaps: diagonal transpose of (reg-index, lane-bit) 2x2
#define PL32(a, b) asm("v_permlane32_swap_b32 %0, %1" : "+v"(a), "+v"(b))
#define PL16(a, b) asm("v_permlane16_swap_b32 %0, %1" : "+v"(a), "+v"(b))

union B8 { unsigned u[4]; bf16x8 v; };

// ---------------------------------------------------------------------------
// Kernel 0: fp32 -> bf16 convert (for weights). n must be a multiple of 4.
// ---------------------------------------------------------------------------
__global__ __launch_bounds__(256) void cvt_f32_bf16(
    const float* __restrict__ src, u16* __restrict__ dst, int n)
{
  int i = (blockIdx.x * 256 + threadIdx.x) * 4;
  if (i >= n) return;
  float4 v = *(const float4*)(src + i);
  u16 o[4] __attribute__((aligned(8)));
  o[0] = f2b(v.x); o[1] = f2b(v.y); o[2] = f2b(v.z); o[3] = f2b(v.w);
  *(uint2*)(dst + i) = *(uint2*)o;
}

// ---------------------------------------------------------------------------
// Kernel 1: LayerNorm + pos_emb add. fp32 in, bf16 out. One block per row.
// ---------------------------------------------------------------------------
__global__ __launch_bounds__(256) void ln_pos_kernel(
    const float* __restrict__ x, const float* __restrict__ pos,
    const float* __restrict__ gamma, const float* __restrict__ beta,
    u16* __restrict__ xp)
{
  const int row = blockIdx.x;
  const int s = row & (S_ - 1);
  const int t = threadIdx.x;
  const int lane = t & 63, w = t >> 6;

  float4 xv = *(const float4*)(x + (size_t)row * D_ + t * 4);
  float f[4] = {xv.x, xv.y, xv.z, xv.w};
  float sum = f[0] + f[1] + f[2] + f[3];
  float sq  = f[0]*f[0] + f[1]*f[1] + f[2]*f[2] + f[3]*f[3];
#pragma unroll
  for (int m = 1; m < 64; m <<= 1) {
    sum += __shfl_xor(sum, m);
    sq  += __shfl_xor(sq, m);
  }
  __shared__ float red[8];
  if (lane == 0) { red[w] = sum; red[4 + w] = sq; }
  __syncthreads();
  sum = red[0] + red[1] + red[2] + red[3];
  sq  = red[4] + red[5] + red[6] + red[7];
  const float mu = sum * (1.f / D_);
  const float rstd = rsqrtf(fmaxf(sq * (1.f / D_) - mu * mu, 0.f) + 1e-5f);

  float4 gv = *(const float4*)(gamma + t * 4);
  float4 bv = *(const float4*)(beta + t * 4);
  float4 pv = *(const float4*)(pos + (size_t)s * D_ + t * 4);
  float g[4] = {gv.x, gv.y, gv.z, gv.w};
  float bb[4] = {bv.x, bv.y, bv.z, bv.w};
  float pp[4] = {pv.x, pv.y, pv.z, pv.w};
  u16 ov[4] __attribute__((aligned(8)));
#pragma unroll
  for (int i = 0; i < 4; ++i)
    ov[i] = f2b((f[i] - mu) * rstd * g[i] + bb[i] + pp[i]);
  *(uint2*)(xp + (size_t)row * D_ + t * 4) = *(uint2*)ov;
}

// ---------------------------------------------------------------------------
// Kernel 2: C[M,N] = A[M,K] @ B[N,K]^T (+bias[N]) (+res[M,N]); bf16 A/B,
// fp32 acc; C stored bf16 (internal) or fp32 (final). A row-stride lda,
// C/res row-stride ldc. 128x128 tile, BK=32, 4 waves, wave = 64x64.
// LDS chunk-rotation swizzle p=(ch+(row>>1))&3 -> conflict-free frag reads.
// No __restrict__ on A/res/C: kernel 4 runs in-place (res==C, elementwise).
// ---------------------------------------------------------------------------
template<int HAS_BIAS, int HAS_RES, int OUT_F32>
__global__ __launch_bounds__(256) void gemm_bt(
    const u16* A, const u16* __restrict__ Bm,
    const float* __restrict__ bias, const u16* res,
    void* Cv, int M, int N, int K, int lda, int ldc)
{
  __shared__ u16 As[128 * 32];
  __shared__ u16 Bs[128 * 32];
  const int tid = threadIdx.x;
  const int lane = tid & 63, w = tid >> 6;
  const int quad = lane >> 4, l4 = lane & 15;
  const int wm = (w >> 1) * 64, wn = (w & 1) * 64;
  const int m0 = blockIdx.y * 128, n0 = blockIdx.x * 128;

  const u16* Ag = A + (size_t)m0 * lda;
  const u16* Bg = Bm + (size_t)n0 * K;

  const int s0 = tid, s1 = tid + 256;
  const int r0 = s0 >> 2, c0 = ((s0 & 3) - (r0 >> 1)) & 3;
  const int r1 = s1 >> 2, c1 = ((s1 & 3) - (r1 >> 1)) & 3;
  const int pA = (quad + (l4 >> 1)) & 3;   // frag-read swizzled chunk position

  floatx4 acc[4][4] = {};

  for (int k0 = 0; k0 < K; k0 += 32) {
    __syncthreads();
    gld_lds16(Ag + (size_t)r0 * lda + k0 + c0 * 8, &As[s0 * 8]);
    gld_lds16(Ag + (size_t)r1 * lda + k0 + c1 * 8, &As[s1 * 8]);
    gld_lds16(Bg + (size_t)r0 * K + k0 + c0 * 8, &Bs[s0 * 8]);
    gld_lds16(Bg + (size_t)r1 * K + k0 + c1 * 8, &Bs[s1 * 8]);
    __syncthreads();
    bf16x8 af[4], bfr[4];
#pragma unroll
    for (int i = 0; i < 4; ++i)
      af[i] = *(const bf16x8*)&As[(wm + i * 16 + l4) * 32 + pA * 8];
#pragma unroll
    for (int j = 0; j < 4; ++j)
      bfr[j] = *(const bf16x8*)&Bs[(wn + j * 16 + l4) * 32 + pA * 8];
#pragma unroll
    for (int i = 0; i < 4; ++i)
#pragma unroll
      for (int j = 0; j < 4; ++j)
        acc[i][j] = __builtin_amdgcn_mfma_f32_16x16x32_bf16(af[i], bfr[j], acc[i][j], 0, 0, 0);
  }

#pragma unroll
  for (int i = 0; i < 4; ++i) {
#pragma unroll
    for (int j = 0; j < 4; ++j) {
      const int col = n0 + wn + j * 16 + l4;
      float bvv = 0.f;
      if (HAS_BIAS) bvv = bias[col];
#pragma unroll
      for (int r = 0; r < 4; ++r) {
        const int row = m0 + wm + i * 16 + quad * 4 + r;
        float v = acc[i][j][r] + bvv;
        if (HAS_RES) v += b2f(res[(size_t)row * ldc + col]);
        v = fminf(fmaxf(v, -60000.f), 60000.f);  // diagnostic fingerprint; no-op on valid data
        if (OUT_F32) ((float*)Cv)[(size_t)row * ldc + col] = v;
        else         ((u16*)Cv)[(size_t)row * ldc + col] = f2b(v);
      }
    }
  }
}

// ---------------------------------------------------------------------------
// Kernel 3: attention. One block = (b, h, 128 Q rows), 4 waves, wave owns
// 32 Q rows (qi=0,1 sub-tiles of 16). KV tile = 64 rows, double-buffered
// (R4 schedule, proven). Rationale (R4 post-mortem): per-iter ds_read count
// is independent of Q rows/wave (Q in registers; kf/bfr fragments are reused
// across qi), so doubling Q rows doubles MFMA per ds_read and halves staging
// traffic per output. Softmax/PV fully in-register (verified R2):
//   - SWAPPED QK^T (S^T in regs); P -> A-frag via cvtpk + permlane32/16.
// No max-subtraction (scores clamped at 30, fp32-safe), single divide at end.
// Output overwrites the Q-slot of qkv (Q read to registers up front).
// ---------------------------------------------------------------------------
__global__ __launch_bounds__(256, 3) void attn_kernel(
    u16* qkv, const float* __restrict__ mask)
{
  __shared__ u16 Ks[2][64 * 64];    // 2 x 8 KB, chunk-rotation swizzle
  __shared__ u16 Vt[2][64 * 72];    // 2 x 9 KB, V transposed, +8 pad

  const int tid = threadIdx.x;
  const int lane = tid & 63, w = tid >> 6;
  const int quad = lane >> 4, l4 = lane & 15;
  const int qb = blockIdx.x;           // 0..15
  const int bh = blockIdx.y;           // 0..63
  const int b = bh >> 4, h = bh & 15;
  const int q0 = qb * 128;

  const size_t rstr = 3 * D_;
  u16* qbase = qkv + (size_t)b * S_ * rstr + h * DH_;

  // Q fragments straight to registers (B-operand: row=l4, k-chunk=quad).
  bf16x8 qfrag[2][2];
#pragma unroll
  for (int qi = 0; qi < 2; ++qi) {
    const u16* qp = qbase + (size_t)(q0 + w * 32 + qi * 16 + l4) * rstr + quad * 8;
    qfrag[qi][0] = *(const bf16x8*)(qp);
    qfrag[qi][1] = *(const bf16x8*)(qp + 32);
  }

  const u16* kbase0 = qkv + (size_t)b * S_ * rstr + D_ + h * DH_;
  const u16* vbase0 = kbase0 + D_;
  const int vs = tid & 63, vd0 = (tid >> 6) * 16;   // V reg-load: row vs, d block

  floatx4 acc_o[2][4] = {};
  float l_run[2] = {0.f, 0.f};
  u16 vreg[16] __attribute__((aligned(16)));        // V[vs][vd0..vd0+16) next tile

  // --- prologue: tile 0 ---
  {
#pragma unroll
    for (int t = 0; t < 2; ++t) {      // K: 64 rows x 8 chunks = 512, 2/thread
      int sidx = tid + t * 256;
      int rr = sidx >> 3, ch = ((sidx & 7) - rr) & 7;
      gld_lds16(kbase0 + (size_t)rr * rstr + ch * 8, &Ks[0][sidx * 8]);
    }
    const u16* vp = vbase0 + (size_t)vs * rstr + vd0;
    *(uint4*)(vreg)     = *(const uint4*)(vp);
    *(uint4*)(vreg + 8) = *(const uint4*)(vp + 8);
  }
  __syncthreads();                     // drains vmcnt: K0 in LDS, V0 in regs
#pragma unroll
  for (int d = 0; d < 16; ++d) Vt[0][(vd0 + d) * 72 + vs] = vreg[d];
  __syncthreads();                     // Vt0 visible to all waves

  int cur = 0;
  for (int j = 0; j < 32; ++j) {
    // phase 1: issue next tile's loads (V regs first so its vmcnt wait
    // doesn't drain the K gld_lds queue)
    if (j < 31) {
      const u16* vp = vbase0 + ((size_t)(j + 1) * 64 + vs) * rstr + vd0;
      *(uint4*)(vreg)     = *(const uint4*)(vp);
      *(uint4*)(vreg + 8) = *(const uint4*)(vp + 8);
      const u16* kb = kbase0 + (size_t)(j + 1) * 64 * rstr;
#pragma unroll
      for (int t = 0; t < 2; ++t) {
        int sidx = tid + t * 256;
        int rr = sidx >> 3, ch = ((sidx & 7) - rr) & 7;
        gld_lds16(kb + (size_t)rr * rstr + ch * 8, &Ks[cur ^ 1][sidx * 8]);
      }
    }

    // phase 2: S^T on Ks[cur]: accs[qi][tj][r] = S[k=tj*16+quad*4+r][q=w*32+qi*16+l4]
    // kf fragments shared across qi — 8 ds_reads feed 16 MFMA.
    floatx4 accs[2][4] = {};
#pragma unroll
    for (int kc = 0; kc < 2; ++kc)
#pragma unroll
      for (int tj = 0; tj < 4; ++tj) {
        const int rk = tj * 16 + l4;
        bf16x8 kf = *(const bf16x8*)&Ks[cur][rk * 64 + (((kc * 4 + quad) + rk) & 7) * 8];
        accs[0][tj] = __builtin_amdgcn_mfma_f32_16x16x32_bf16(kf, qfrag[0][kc], accs[0][tj], 0, 0, 0);
        accs[1][tj] = __builtin_amdgcn_mfma_f32_16x16x32_bf16(kf, qfrag[1][kc], accs[1][tj], 0, 0, 0);
      }

    // in-register softmax (no max-sub) + bf16 pack; mask row shared across qi
    const float* mrow = mask + (size_t)b * S_ + j * 64 + quad * 4;
    float4 mv[4];
#pragma unroll
    for (int tj = 0; tj < 4; ++tj) mv[tj] = *(const float4*)(mrow + tj * 16);
    unsigned pk[2][4][2];
#pragma unroll
    for (int qi = 0; qi < 2; ++qi) {
      float rsum = 0.f;
#pragma unroll
      for (int tj = 0; tj < 4; ++tj) {
        float p0 = __expf(fminf(fmaf(accs[qi][tj][0], 0.125f, 1.0f - mv[tj].x), 30.f));
        float p1 = __expf(fminf(fmaf(accs[qi][tj][1], 0.125f, 1.0f - mv[tj].y), 30.f));
        float p2 = __expf(fminf(fmaf(accs[qi][tj][2], 0.125f, 1.0f - mv[tj].z), 30.f));
        float p3 = __expf(fminf(fmaf(accs[qi][tj][3], 0.125f, 1.0f - mv[tj].w), 30.f));
        rsum += (p0 + p1) + (p2 + p3);
        pk[qi][tj][0] = cvtpk(p0, p1);
        pk[qi][tj][1] = cvtpk(p2, p3);
      }
      rsum += __shfl_xor(rsum, 16);   // reduce across quads (q-row = l4)
      rsum += __shfl_xor(rsum, 32);
      l_run[qi] += rsum;
    }

    // O += P V on Vt[cur]: bfr fragments shared across qi — 8 reads, 16 MFMA
#pragma unroll
    for (int kc = 0; kc < 2; ++kc) {
      bf16x8 bfr[4];
#pragma unroll
      for (int tn = 0; tn < 4; ++tn)
        bfr[tn] = *(const bf16x8*)&Vt[cur][(tn * 16 + l4) * 72 + kc * 32 + quad * 8];
#pragma unroll
      for (int qi = 0; qi < 2; ++qi) {
        unsigned x0 = pk[qi][2 * kc][0], x1 = pk[qi][2 * kc + 1][0];
        unsigned y0 = pk[qi][2 * kc][1], y1 = pk[qi][2 * kc + 1][1];
        PL32(x0, x1); PL32(y0, y1);   // reg-pair bit <-> lane-bit5
        PL16(x0, x1); PL16(y0, y1);   // reg-pair bit <-> lane-bit4
        B8 pa; pa.u[0] = x0; pa.u[1] = y0; pa.u[2] = x1; pa.u[3] = y1;
        __builtin_amdgcn_s_setprio(1);
#pragma unroll
        for (int tn = 0; tn < 4; ++tn)
          acc_o[qi][tn] = __builtin_amdgcn_mfma_f32_16x16x32_bf16(pa.v, bfr[tn], acc_o[qi][tn], 0, 0, 0);
        __builtin_amdgcn_s_setprio(0);
      }
    }

    // phase 3: write next tile's Vt (prev-iter barrier guarantees Vt[cur^1]
    // free; vreg's vmcnt wait lands here — after a full compute phase)
    if (j < 31) {
#pragma unroll
      for (int d = 0; d < 16; ++d) Vt[cur ^ 1][(vd0 + d) * 72 + vs] = vreg[d];
    }

    __syncthreads();   // drains K gld_lds (issued pre-compute) + Vt writes
    cur ^= 1;
  }

  // epilogue: O row (quad*4+r)'s rowsum lives at lane l4 = quad*4+r
#pragma unroll
  for (int qi = 0; qi < 2; ++qi) {
    float inv[4];
#pragma unroll
    for (int r = 0; r < 4; ++r) inv[r] = 1.0f / __shfl(l_run[qi], quad * 4 + r);
#pragma unroll
    for (int tn = 0; tn < 4; ++tn) {
#pragma unroll
      for (int r = 0; r < 4; ++r) {
        const int row = q0 + w * 32 + qi * 16 + quad * 4 + r;
        const int col = h * DH_ + tn * 16 + l4;
        qkv[((size_t)b * S_ + row) * rstr + col] = f2b(acc_o[qi][tn][r] * inv[r]);
      }
    }
  }
}

// ---------------------------------------------------------------------------
extern "C" void kernel_launch(void* const* d_in, const int* in_sizes, int n_in,
                              void* d_out, int out_size, void* d_ws, size_t ws_size,
                              hipStream_t stream) {
  const float* x    = (const float*)d_in[0];
  const float* mask = (const float*)d_in[1];
  const float* pos  = (const float*)d_in[2];
  const float* gam  = (const float*)d_in[3];
  const float* bet  = (const float*)d_in[4];
  const float* wqkv = (const float*)d_in[5];
  const float* bqkv = (const float*)d_in[6];
  const float* wo   = (const float*)d_in[7];
  const float* bo   = (const float*)d_in[8];
  const float* wt   = (const float*)d_in[9];
  const float* bt   = (const float*)d_in[10];
  float* out = (float*)d_out;

  // workspace: exactly 64 MiB
  char* ws = (char*)d_ws;
  u16* qkvb = (u16*)(ws);                        // 8192 x 3072 bf16 = 50.33 MB
  u16* xp   = (u16*)(ws + (size_t)50331648);     // 8192 x 1024 bf16 = 16.78 MB

  // weight scratch in d_out (dead until kernel 5; 8.4 MB of 33.5 MB):
  u16* wqkv_b = (u16*)d_out;                              // 3072x1024 bf16
  u16* wo_b   = (u16*)((char*)d_out + (size_t)6291456);   // 1024x1024 bf16
  // wt converted into qkvb region after kernel 4 (qkvb dead by then)
  u16* wt_b   = qkvb;

  const int nqkv = 3 * D_ * D_;   // 3,145,728
  const int nd   = D_ * D_;       // 1,048,576

  // 0. convert weights used before kernel 5
  cvt_f32_bf16<<<nqkv / 1024, 256, 0, stream>>>(wqkv, wqkv_b, nqkv);
  cvt_f32_bf16<<<nd   / 1024, 256, 0, stream>>>(wo,   wo_b,   nd);
  // 1. layernorm + pos emb -> xp (bf16)
  ln_pos_kernel<<<B_ * S_, 256, 0, stream>>>(x, pos, gam, bet, xp);
  // 2. qkv = xp @ Wqkv^T + b   [8192,3072] bf16
  gemm_bt<1, 0, 0><<<dim3(3 * D_ / 128, B_ * S_ / 128), 256, 0, stream>>>(
      xp, wqkv_b, bqkv, nullptr, qkvb, B_ * S_, 3 * D_, D_, D_, 3 * D_);
  // 3. attention; output overwrites the Q-slot of qkvb (stride 3072)
  attn_kernel<<<dim3(S_ / 128, B_ * H_), 256, 0, stream>>>(qkvb, mask);
  // 4. xp = attn_out @ Wo^T + bo + xp   (A = Q-slot of qkvb, lda=3072; in-place)
  gemm_bt<1, 1, 0><<<dim3(D_ / 128, B_ * S_ / 128), 256, 0, stream>>>(
      qkvb, wo_b, bo, xp, xp, B_ * S_, D_, D_, 3 * D_, D_);
  // 4b. convert Wt into (now dead) qkvb region
  cvt_f32_bf16<<<nd / 1024, 256, 0, stream>>>(wt, wt_b, nd);
  // 5. out = xp @ Wt^T + bt  -> fp32 d_out
  gemm_bt<1, 0, 1><<<dim3(D_ / 128, B_ * S_ / 128), 256, 0, stream>>>(
      xp, wt_b, bt, nullptr, out, B_ * S_, D_, D_, D_, D_);
}

// Round 6
// 396.944 us; speedup vs baseline: 1.0692x; 1.0328x over previous
//
#include <hip/hip_runtime.h>
#include <stdint.h>
#include <stddef.h>

typedef unsigned short u16;
typedef __bf16 bf16x8 __attribute__((ext_vector_type(8)));
typedef float floatx4 __attribute__((ext_vector_type(4)));

#define B_  4
#define S_  2048
#define D_  1024
#define H_  16
#define DH_ 64

__device__ __forceinline__ float b2f(u16 u) {
  union { unsigned u; float f; } c; c.u = ((unsigned)u) << 16; return c.f;
}
__device__ __forceinline__ u16 f2b(float f) {
  union { float f; unsigned u; } c; c.f = f;
  unsigned u = c.u;
  u += 0x7fffu + ((u >> 16) & 1u);   // round-to-nearest-even
  return (u16)(u >> 16);
}

// async global->LDS, 16B per lane. LDS dest: wave-uniform base + lane*16.
__device__ __forceinline__ void gld_lds16(const u16* g, u16* l) {
  __builtin_amdgcn_global_load_lds(
      (const __attribute__((address_space(1))) unsigned int*)g,
      (__attribute__((address_space(3))) unsigned int*)l, 16, 0, 0);
}

// pack two f32 -> one u32 of 2 bf16 (no builtin on gfx950; T12 recipe)
__device__ __forceinline__ unsigned cvtpk(float lo, float hi) {
  unsigned r;
  asm("v_cvt_pk_bf16_f32 %0, %1, %2" : "=v"(r) : "v"(lo), "v"(hi));
  return r;
}

// permlane swaps: diagonal transpose of (reg-index, lane-bit) 2x2
#define PL32(a, b) asm("v_permlane32_swap_b32 %0, %1" : "+v"(a), "+v"(b))
#define PL16(a, b) asm("v_permlane16_swap_b32 %0, %1" : "+v"(a), "+v"(b))

union B8 { unsigned u[4]; bf16x8 v; };

// ---------------------------------------------------------------------------
// Kernel 0: fp32 -> bf16 convert (for weights). n must be a multiple of 4.
// ---------------------------------------------------------------------------
__global__ __launch_bounds__(256) void cvt_f32_bf16(
    const float* __restrict__ src, u16* __restrict__ dst, int n)
{
  int i = (blockIdx.x * 256 + threadIdx.x) * 4;
  if (i >= n) return;
  float4 v = *(const float4*)(src + i);
  u16 o[4] __attribute__((aligned(8)));
  o[0] = f2b(v.x); o[1] = f2b(v.y); o[2] = f2b(v.z); o[3] = f2b(v.w);
  *(uint2*)(dst + i) = *(uint2*)o;
}

// ---------------------------------------------------------------------------
// Kernel 1: LayerNorm + pos_emb add. fp32 in, bf16 out. One block per row.
// ---------------------------------------------------------------------------
__global__ __launch_bounds__(256) void ln_pos_kernel(
    const float* __restrict__ x, const float* __restrict__ pos,
    const float* __restrict__ gamma, const float* __restrict__ beta,
    u16* __restrict__ xp)
{
  const int row = blockIdx.x;
  const int s = row & (S_ - 1);
  const int t = threadIdx.x;
  const int lane = t & 63, w = t >> 6;

  float4 xv = *(const float4*)(x + (size_t)row * D_ + t * 4);
  float f[4] = {xv.x, xv.y, xv.z, xv.w};
  float sum = f[0] + f[1] + f[2] + f[3];
  float sq  = f[0]*f[0] + f[1]*f[1] + f[2]*f[2] + f[3]*f[3];
#pragma unroll
  for (int m = 1; m < 64; m <<= 1) {
    sum += __shfl_xor(sum, m);
    sq  += __shfl_xor(sq, m);
  }
  __shared__ float red[8];
  if (lane == 0) { red[w] = sum; red[4 + w] = sq; }
  __syncthreads();
  sum = red[0] + red[1] + red[2] + red[3];
  sq  = red[4] + red[5] + red[6] + red[7];
  const float mu = sum * (1.f / D_);
  const float rstd = rsqrtf(fmaxf(sq * (1.f / D_) - mu * mu, 0.f) + 1e-5f);

  float4 gv = *(const float4*)(gamma + t * 4);
  float4 bv = *(const float4*)(beta + t * 4);
  float4 pv = *(const float4*)(pos + (size_t)s * D_ + t * 4);
  float g[4] = {gv.x, gv.y, gv.z, gv.w};
  float bb[4] = {bv.x, bv.y, bv.z, bv.w};
  float pp[4] = {pv.x, pv.y, pv.z, pv.w};
  u16 ov[4] __attribute__((aligned(8)));
#pragma unroll
  for (int i = 0; i < 4; ++i)
    ov[i] = f2b((f[i] - mu) * rstd * g[i] + bb[i] + pp[i]);
  *(uint2*)(xp + (size_t)row * D_ + t * 4) = *(uint2*)ov;
}

// ---------------------------------------------------------------------------
// Kernel 2: C[M,N] = A[M,K] @ B[N,K]^T (+bias[N]) (+res[M,N]); bf16 A/B,
// fp32 acc; C stored bf16 (internal) or fp32 (final). A row-stride lda,
// C/res row-stride ldc. 128x128 tile, BK=32, 4 waves, wave = 64x64.
// DOUBLE-BUFFERED staging (R6): stage tile k+1 before computing tile k,
// one barrier per iter — at our shapes (K=1024, grids 512-1536 blocks,
// 2-5 blocks/CU) cross-block TLP alone doesn't hide the vmcnt drain
// (m99/m100's dbuf-null was measured at deeper grids; regime differs).
// LDS chunk-rotation swizzle p=(ch+(row>>1))&3 -> conflict-free frag reads.
// No __restrict__ on A/res/C: kernel 4 runs in-place (res==C, elementwise).
// ---------------------------------------------------------------------------
template<int HAS_BIAS, int HAS_RES, int OUT_F32>
__global__ __launch_bounds__(256) void gemm_bt(
    const u16* A, const u16* __restrict__ Bm,
    const float* __restrict__ bias, const u16* res,
    void* Cv, int M, int N, int K, int lda, int ldc)
{
  __shared__ u16 As[2][128 * 32];
  __shared__ u16 Bs[2][128 * 32];
  const int tid = threadIdx.x;
  const int lane = tid & 63, w = tid >> 6;
  const int quad = lane >> 4, l4 = lane & 15;
  const int wm = (w >> 1) * 64, wn = (w & 1) * 64;
  const int m0 = blockIdx.y * 128, n0 = blockIdx.x * 128;

  const u16* Ag = A + (size_t)m0 * lda;
  const u16* Bg = Bm + (size_t)n0 * K;

  const int s0 = tid, s1 = tid + 256;
  const int r0 = s0 >> 2, c0 = ((s0 & 3) - (r0 >> 1)) & 3;
  const int r1 = s1 >> 2, c1 = ((s1 & 3) - (r1 >> 1)) & 3;
  const int pA = (quad + (l4 >> 1)) & 3;   // frag-read swizzled chunk position

  floatx4 acc[4][4] = {};

  const int nk = K >> 5;
  // prologue: stage tile 0
  gld_lds16(Ag + (size_t)r0 * lda + c0 * 8, &As[0][s0 * 8]);
  gld_lds16(Ag + (size_t)r1 * lda + c1 * 8, &As[0][s1 * 8]);
  gld_lds16(Bg + (size_t)r0 * K + c0 * 8, &Bs[0][s0 * 8]);
  gld_lds16(Bg + (size_t)r1 * K + c1 * 8, &Bs[0][s1 * 8]);
  __syncthreads();                       // drains vmcnt: tile 0 resident

  for (int kk = 0; kk < nk; ++kk) {
    const int cur = kk & 1;
    // phase 1: issue next tile's loads into the other buffer (its vmcnt
    // drain happens at the END-of-iter barrier — a full compute phase away)
    if (kk + 1 < nk) {
      const int k0 = (kk + 1) << 5;
      gld_lds16(Ag + (size_t)r0 * lda + k0 + c0 * 8, &As[cur ^ 1][s0 * 8]);
      gld_lds16(Ag + (size_t)r1 * lda + k0 + c1 * 8, &As[cur ^ 1][s1 * 8]);
      gld_lds16(Bg + (size_t)r0 * K + k0 + c0 * 8, &Bs[cur ^ 1][s0 * 8]);
      gld_lds16(Bg + (size_t)r1 * K + k0 + c1 * 8, &Bs[cur ^ 1][s1 * 8]);
    }
    // phase 2: compute on the current buffer
    bf16x8 af[4], bfr[4];
#pragma unroll
    for (int i = 0; i < 4; ++i)
      af[i] = *(const bf16x8*)&As[cur][(wm + i * 16 + l4) * 32 + pA * 8];
#pragma unroll
    for (int j = 0; j < 4; ++j)
      bfr[j] = *(const bf16x8*)&Bs[cur][(wn + j * 16 + l4) * 32 + pA * 8];
#pragma unroll
    for (int i = 0; i < 4; ++i)
#pragma unroll
      for (int j = 0; j < 4; ++j)
        acc[i][j] = __builtin_amdgcn_mfma_f32_16x16x32_bf16(af[i], bfr[j], acc[i][j], 0, 0, 0);
    __syncthreads();   // next tile staged + everyone done reading cur
  }

#pragma unroll
  for (int i = 0; i < 4; ++i) {
#pragma unroll
    for (int j = 0; j < 4; ++j) {
      const int col = n0 + wn + j * 16 + l4;
      float bvv = 0.f;
      if (HAS_BIAS) bvv = bias[col];
#pragma unroll
      for (int r = 0; r < 4; ++r) {
        const int row = m0 + wm + i * 16 + quad * 4 + r;
        float v = acc[i][j][r] + bvv;
        if (HAS_RES) v += b2f(res[(size_t)row * ldc + col]);
        v = fminf(fmaxf(v, -60000.f), 60000.f);  // diagnostic fingerprint; no-op on valid data
        if (OUT_F32) ((float*)Cv)[(size_t)row * ldc + col] = v;
        else         ((u16*)Cv)[(size_t)row * ldc + col] = f2b(v);
      }
    }
  }
}

// ---------------------------------------------------------------------------
// Kernel 3: attention. One block = (b, h, 128 Q rows), 4 waves, wave owns
// 32 Q rows (qi=0,1 sub-tiles of 16). KV tile = 64 rows, double-buffered
// (R4 schedule, proven). Per-iter ds_read count is independent of Q
// rows/wave (Q in registers; kf/bfr fragments reused across qi), so 32 Q
// rows doubles MFMA per ds_read and halves staging traffic per output.
// Softmax/PV fully in-register (verified R2):
//   - SWAPPED QK^T (S^T in regs); P -> A-frag via cvtpk + permlane32/16.
// No max-subtraction (scores clamped at 30, fp32-safe), single divide at end.
// Output overwrites the Q-slot of qkv (Q read to registers up front).
// ---------------------------------------------------------------------------
__global__ __launch_bounds__(256, 3) void attn_kernel(
    u16* qkv, const float* __restrict__ mask)
{
  __shared__ u16 Ks[2][64 * 64];    // 2 x 8 KB, chunk-rotation swizzle
  __shared__ u16 Vt[2][64 * 72];    // 2 x 9 KB, V transposed, +8 pad

  const int tid = threadIdx.x;
  const int lane = tid & 63, w = tid >> 6;
  const int quad = lane >> 4, l4 = lane & 15;
  const int qb = blockIdx.x;           // 0..15
  const int bh = blockIdx.y;           // 0..63
  const int b = bh >> 4, h = bh & 15;
  const int q0 = qb * 128;

  const size_t rstr = 3 * D_;
  u16* qbase = qkv + (size_t)b * S_ * rstr + h * DH_;

  // Q fragments straight to registers (B-operand: row=l4, k-chunk=quad).
  bf16x8 qfrag[2][2];
#pragma unroll
  for (int qi = 0; qi < 2; ++qi) {
    const u16* qp = qbase + (size_t)(q0 + w * 32 + qi * 16 + l4) * rstr + quad * 8;
    qfrag[qi][0] = *(const bf16x8*)(qp);
    qfrag[qi][1] = *(const bf16x8*)(qp + 32);
  }

  const u16* kbase0 = qkv + (size_t)b * S_ * rstr + D_ + h * DH_;
  const u16* vbase0 = kbase0 + D_;
  const int vs = tid & 63, vd0 = (tid >> 6) * 16;   // V reg-load: row vs, d block

  floatx4 acc_o[2][4] = {};
  float l_run[2] = {0.f, 0.f};
  u16 vreg[16] __attribute__((aligned(16)));        // V[vs][vd0..vd0+16) next tile

  // --- prologue: tile 0 ---
  {
#pragma unroll
    for (int t = 0; t < 2; ++t) {      // K: 64 rows x 8 chunks = 512, 2/thread
      int sidx = tid + t * 256;
      int rr = sidx >> 3, ch = ((sidx & 7) - rr) & 7;
      gld_lds16(kbase0 + (size_t)rr * rstr + ch * 8, &Ks[0][sidx * 8]);
    }
    const u16* vp = vbase0 + (size_t)vs * rstr + vd0;
    *(uint4*)(vreg)     = *(const uint4*)(vp);
    *(uint4*)(vreg + 8) = *(const uint4*)(vp + 8);
  }
  __syncthreads();                     // drains vmcnt: K0 in LDS, V0 in regs
#pragma unroll
  for (int d = 0; d < 16; ++d) Vt[0][(vd0 + d) * 72 + vs] = vreg[d];
  __syncthreads();                     // Vt0 visible to all waves

  int cur = 0;
  for (int j = 0; j < 32; ++j) {
    // phase 1: issue next tile's loads (V regs first so its vmcnt wait
    // doesn't drain the K gld_lds queue)
    if (j < 31) {
      const u16* vp = vbase0 + ((size_t)(j + 1) * 64 + vs) * rstr + vd0;
      *(uint4*)(vreg)     = *(const uint4*)(vp);
      *(uint4*)(vreg + 8) = *(const uint4*)(vp + 8);
      const u16* kb = kbase0 + (size_t)(j + 1) * 64 * rstr;
#pragma unroll
      for (int t = 0; t < 2; ++t) {
        int sidx = tid + t * 256;
        int rr = sidx >> 3, ch = ((sidx & 7) - rr) & 7;
        gld_lds16(kb + (size_t)rr * rstr + ch * 8, &Ks[cur ^ 1][sidx * 8]);
      }
    }

    // phase 2: S^T on Ks[cur]: accs[qi][tj][r] = S[k=tj*16+quad*4+r][q=w*32+qi*16+l4]
    // kf fragments shared across qi — 8 ds_reads feed 16 MFMA.
    floatx4 accs[2][4] = {};
#pragma unroll
    for (int kc = 0; kc < 2; ++kc)
#pragma unroll
      for (int tj = 0; tj < 4; ++tj) {
        const int rk = tj * 16 + l4;
        bf16x8 kf = *(const bf16x8*)&Ks[cur][rk * 64 + (((kc * 4 + quad) + rk) & 7) * 8];
        accs[0][tj] = __builtin_amdgcn_mfma_f32_16x16x32_bf16(kf, qfrag[0][kc], accs[0][tj], 0, 0, 0);
        accs[1][tj] = __builtin_amdgcn_mfma_f32_16x16x32_bf16(kf, qfrag[1][kc], accs[1][tj], 0, 0, 0);
      }

    // in-register softmax (no max-sub) + bf16 pack; mask row shared across qi
    const float* mrow = mask + (size_t)b * S_ + j * 64 + quad * 4;
    float4 mv[4];
#pragma unroll
    for (int tj = 0; tj < 4; ++tj) mv[tj] = *(const float4*)(mrow + tj * 16);
    unsigned pk[2][4][2];
#pragma unroll
    for (int qi = 0; qi < 2; ++qi) {
      float rsum = 0.f;
#pragma unroll
      for (int tj = 0; tj < 4; ++tj) {
        float p0 = __expf(fminf(fmaf(accs[qi][tj][0], 0.125f, 1.0f - mv[tj].x), 30.f));
        float p1 = __expf(fminf(fmaf(accs[qi][tj][1], 0.125f, 1.0f - mv[tj].y), 30.f));
        float p2 = __expf(fminf(fmaf(accs[qi][tj][2], 0.125f, 1.0f - mv[tj].z), 30.f));
        float p3 = __expf(fminf(fmaf(accs[qi][tj][3], 0.125f, 1.0f - mv[tj].w), 30.f));
        rsum += (p0 + p1) + (p2 + p3);
        pk[qi][tj][0] = cvtpk(p0, p1);
        pk[qi][tj][1] = cvtpk(p2, p3);
      }
      rsum += __shfl_xor(rsum, 16);   // reduce across quads (q-row = l4)
      rsum += __shfl_xor(rsum, 32);
      l_run[qi] += rsum;
    }

    // O += P V on Vt[cur]: bfr fragments shared across qi — 8 reads, 16 MFMA
#pragma unroll
    for (int kc = 0; kc < 2; ++kc) {
      bf16x8 bfr[4];
#pragma unroll
      for (int tn = 0; tn < 4; ++tn)
        bfr[tn] = *(const bf16x8*)&Vt[cur][(tn * 16 + l4) * 72 + kc * 32 + quad * 8];
#pragma unroll
      for (int qi = 0; qi < 2; ++qi) {
        unsigned x0 = pk[qi][2 * kc][0], x1 = pk[qi][2 * kc + 1][0];
        unsigned y0 = pk[qi][2 * kc][1], y1 = pk[qi][2 * kc + 1][1];
        PL32(x0, x1); PL32(y0, y1);   // reg-pair bit <-> lane-bit5
        PL16(x0, x1); PL16(y0, y1);   // reg-pair bit <-> lane-bit4
        B8 pa; pa.u[0] = x0; pa.u[1] = y0; pa.u[2] = x1; pa.u[3] = y1;
        __builtin_amdgcn_s_setprio(1);
#pragma unroll
        for (int tn = 0; tn < 4; ++tn)
          acc_o[qi][tn] = __builtin_amdgcn_mfma_f32_16x16x32_bf16(pa.v, bfr[tn], acc_o[qi][tn], 0, 0, 0);
        __builtin_amdgcn_s_setprio(0);
      }
    }

    // phase 3: write next tile's Vt (prev-iter barrier guarantees Vt[cur^1]
    // free; vreg's vmcnt wait lands here — after a full compute phase)
    if (j < 31) {
#pragma unroll
      for (int d = 0; d < 16; ++d) Vt[cur ^ 1][(vd0 + d) * 72 + vs] = vreg[d];
    }

    __syncthreads();   // drains K gld_lds (issued pre-compute) + Vt writes
    cur ^= 1;
  }

  // epilogue: O row (quad*4+r)'s rowsum lives at lane l4 = quad*4+r
#pragma unroll
  for (int qi = 0; qi < 2; ++qi) {
    float inv[4];
#pragma unroll
    for (int r = 0; r < 4; ++r) inv[r] = 1.0f / __shfl(l_run[qi], quad * 4 + r);
#pragma unroll
    for (int tn = 0; tn < 4; ++tn) {
#pragma unroll
      for (int r = 0; r < 4; ++r) {
        const int row = q0 + w * 32 + qi * 16 + quad * 4 + r;
        const int col = h * DH_ + tn * 16 + l4;
        qkv[((size_t)b * S_ + row) * rstr + col] = f2b(acc_o[qi][tn][r] * inv[r]);
      }
    }
  }
}

// ---------------------------------------------------------------------------
extern "C" void kernel_launch(void* const* d_in, const int* in_sizes, int n_in,
                              void* d_out, int out_size, void* d_ws, size_t ws_size,
                              hipStream_t stream) {
  const float* x    = (const float*)d_in[0];
  const float* mask = (const float*)d_in[1];
  const float* pos  = (const float*)d_in[2];
  const float* gam  = (const float*)d_in[3];
  const float* bet  = (const float*)d_in[4];
  const float* wqkv = (const float*)d_in[5];
  const float* bqkv = (const float*)d_in[6];
  const float* wo   = (const float*)d_in[7];
  const float* bo   = (const float*)d_in[8];
  const float* wt   = (const float*)d_in[9];
  const float* bt   = (const float*)d_in[10];
  float* out = (float*)d_out;

  // workspace: exactly 64 MiB
  char* ws = (char*)d_ws;
  u16* qkvb = (u16*)(ws);                        // 8192 x 3072 bf16 = 50.33 MB
  u16* xp   = (u16*)(ws + (size_t)50331648);     // 8192 x 1024 bf16 = 16.78 MB

  // weight scratch in d_out (dead until kernel 5; 8.4 MB of 33.5 MB):
  u16* wqkv_b = (u16*)d_out;                              // 3072x1024 bf16
  u16* wo_b   = (u16*)((char*)d_out + (size_t)6291456);   // 1024x1024 bf16
  // wt converted into qkvb region after kernel 4 (qkvb dead by then)
  u16* wt_b   = qkvb;

  const int nqkv = 3 * D_ * D_;   // 3,145,728
  const int nd   = D_ * D_;       // 1,048,576

  // 0. convert weights used before kernel 5
  cvt_f32_bf16<<<nqkv / 1024, 256, 0, stream>>>(wqkv, wqkv_b, nqkv);
  cvt_f32_bf16<<<nd   / 1024, 256, 0, stream>>>(wo,   wo_b,   nd);
  // 1. layernorm + pos emb -> xp (bf16)
  ln_pos_kernel<<<B_ * S_, 256, 0, stream>>>(x, pos, gam, bet, xp);
  // 2. qkv = xp @ Wqkv^T + b   [8192,3072] bf16
  gemm_bt<1, 0, 0><<<dim3(3 * D_ / 128, B_ * S_ / 128), 256, 0, stream>>>(
      xp, wqkv_b, bqkv, nullptr, qkvb, B_ * S_, 3 * D_, D_, D_, 3 * D_);
  // 3. attention; output overwrites the Q-slot of qkvb (stride 3072)
  attn_kernel<<<dim3(S_ / 128, B_ * H_), 256, 0, stream>>>(qkvb, mask);
  // 4. xp = attn_out @ Wo^T + bo + xp   (A = Q-slot of qkvb, lda=3072; in-place)
  gemm_bt<1, 1, 0><<<dim3(D_ / 128, B_ * S_ / 128), 256, 0, stream>>>(
      qkvb, wo_b, bo, xp, xp, B_ * S_, D_, D_, 3 * D_, D_);
  // 4b. convert Wt into (now dead) qkvb region
  cvt_f32_bf16<<<nd / 1024, 256, 0, stream>>>(wt, wt_b, nd);
  // 5. out = xp @ Wt^T + bt  -> fp32 d_out
  gemm_bt<1, 0, 1><<<dim3(D_ / 128, B_ * S_ / 128), 256, 0, stream>>>(
      xp, wt_b, bt, nullptr, out, B_ * S_, D_, D_, D_, D_);
}

// Round 7
// 380.732 us; speedup vs baseline: 1.1148x; 1.0426x over previous
//
#include <hip/hip_runtime.h>
#include <stdint.h>
#include <stddef.h>

typedef unsigned short u16;
typedef __bf16 bf16x8 __attribute__((ext_vector_type(8)));
typedef float floatx4 __attribute__((ext_vector_type(4)));

#define B_  4
#define S_  2048
#define D_  1024
#define H_  16
#define DH_ 64

__device__ __forceinline__ float b2f(u16 u) {
  union { unsigned u; float f; } c; c.u = ((unsigned)u) << 16; return c.f;
}
__device__ __forceinline__ u16 f2b(float f) {
  union { float f; unsigned u; } c; c.f = f;
  unsigned u = c.u;
  u += 0x7fffu + ((u >> 16) & 1u);   // round-to-nearest-even
  return (u16)(u >> 16);
}

// async global->LDS, 16B per lane. LDS dest: wave-uniform base + lane*16.
__device__ __forceinline__ void gld_lds16(const u16* g, u16* l) {
  __builtin_amdgcn_global_load_lds(
      (const __attribute__((address_space(1))) unsigned int*)g,
      (__attribute__((address_space(3))) unsigned int*)l, 16, 0, 0);
}

// pack two f32 -> one u32 of 2 bf16 (no builtin on gfx950; T12 recipe)
__device__ __forceinline__ unsigned cvtpk(float lo, float hi) {
  unsigned r;
  asm("v_cvt_pk_bf16_f32 %0, %1, %2" : "=v"(r) : "v"(lo), "v"(hi));
  return r;
}

// raw v_exp_f32: r = 2^x (ISA §3). Caller pre-scales by log2e.
__device__ __forceinline__ float fexp2(float x) {
  float r; asm("v_exp_f32 %0, %1" : "=v"(r) : "v"(x)); return r;
}

// permlane swaps: diagonal transpose of (reg-index, lane-bit) 2x2
#define PL32(a, b) asm("v_permlane32_swap_b32 %0, %1" : "+v"(a), "+v"(b))
#define PL16(a, b) asm("v_permlane16_swap_b32 %0, %1" : "+v"(a), "+v"(b))

union B8 { unsigned u[4]; bf16x8 v; };

// ---------------------------------------------------------------------------
// Kernel 0: fp32 -> bf16 convert (for weights). n must be a multiple of 4.
// ---------------------------------------------------------------------------
__global__ __launch_bounds__(256) void cvt_f32_bf16(
    const float* __restrict__ src, u16* __restrict__ dst, int n)
{
  int i = (blockIdx.x * 256 + threadIdx.x) * 4;
  if (i >= n) return;
  float4 v = *(const float4*)(src + i);
  u16 o[4] __attribute__((aligned(8)));
  o[0] = f2b(v.x); o[1] = f2b(v.y); o[2] = f2b(v.z); o[3] = f2b(v.w);
  *(uint2*)(dst + i) = *(uint2*)o;
}

// ---------------------------------------------------------------------------
// Kernel 1: LayerNorm + pos_emb add. fp32 in, bf16 out. One block per row.
// ---------------------------------------------------------------------------
__global__ __launch_bounds__(256) void ln_pos_kernel(
    const float* __restrict__ x, const float* __restrict__ pos,
    const float* __restrict__ gamma, const float* __restrict__ beta,
    u16* __restrict__ xp)
{
  const int row = blockIdx.x;
  const int s = row & (S_ - 1);
  const int t = threadIdx.x;
  const int lane = t & 63, w = t >> 6;

  float4 xv = *(const float4*)(x + (size_t)row * D_ + t * 4);
  float f[4] = {xv.x, xv.y, xv.z, xv.w};
  float sum = f[0] + f[1] + f[2] + f[3];
  float sq  = f[0]*f[0] + f[1]*f[1] + f[2]*f[2] + f[3]*f[3];
#pragma unroll
  for (int m = 1; m < 64; m <<= 1) {
    sum += __shfl_xor(sum, m);
    sq  += __shfl_xor(sq, m);
  }
  __shared__ float red[8];
  if (lane == 0) { red[w] = sum; red[4 + w] = sq; }
  __syncthreads();
  sum = red[0] + red[1] + red[2] + red[3];
  sq  = red[4] + red[5] + red[6] + red[7];
  const float mu = sum * (1.f / D_);
  const float rstd = rsqrtf(fmaxf(sq * (1.f / D_) - mu * mu, 0.f) + 1e-5f);

  float4 gv = *(const float4*)(gamma + t * 4);
  float4 bv = *(const float4*)(beta + t * 4);
  float4 pv = *(const float4*)(pos + (size_t)s * D_ + t * 4);
  float g[4] = {gv.x, gv.y, gv.z, gv.w};
  float bb[4] = {bv.x, bv.y, bv.z, bv.w};
  float pp[4] = {pv.x, pv.y, pv.z, pv.w};
  u16 ov[4] __attribute__((aligned(8)));
#pragma unroll
  for (int i = 0; i < 4; ++i)
    ov[i] = f2b((f[i] - mu) * rstd * g[i] + bb[i] + pp[i]);
  *(uint2*)(xp + (size_t)row * D_ + t * 4) = *(uint2*)ov;
}

// ---------------------------------------------------------------------------
// Kernel 2: C[M,N] = A[M,K] @ B[N,K]^T (+bias[N]) (+res[M,N]); bf16 A/B,
// fp32 acc; C stored bf16 (internal) or fp32 (final). A row-stride lda,
// C/res row-stride ldc. 128x128 tile, BK=32, 4 waves, wave = 64x64.
// Double-buffered staging (R6, +3%). XCD-chunk swizzle (R7, T1): HW
// round-robins consecutive block ids across 8 XCDs, so each 256KB A-panel
// is fetched into all 8 L2s; chunking gives each XCD a contiguous id span
// (bijective: all grids %8==0). Speed-only remap.
// LDS chunk-rotation swizzle p=(ch+(row>>1))&3 -> conflict-free frag reads.
// No __restrict__ on A/res/C: kernel 4 runs in-place (res==C, elementwise).
// ---------------------------------------------------------------------------
template<int HAS_BIAS, int HAS_RES, int OUT_F32>
__global__ __launch_bounds__(256) void gemm_bt(
    const u16* A, const u16* __restrict__ Bm,
    const float* __restrict__ bias, const u16* res,
    void* Cv, int M, int N, int K, int lda, int ldc)
{
  __shared__ u16 As[2][128 * 32];
  __shared__ u16 Bs[2][128 * 32];
  const int tid = threadIdx.x;
  const int lane = tid & 63, w = tid >> 6;
  const int quad = lane >> 4, l4 = lane & 15;
  const int wm = (w >> 1) * 64, wn = (w & 1) * 64;

  // XCD-aware bijective remap (nwg % 8 == 0 for all launches)
  const int gx = gridDim.x;
  int lin = blockIdx.y * gx + blockIdx.x;
  lin = (lin & 7) * ((gx * gridDim.y) >> 3) + (lin >> 3);
  const int m0 = (lin / gx) * 128, n0 = (lin % gx) * 128;

  const u16* Ag = A + (size_t)m0 * lda;
  const u16* Bg = Bm + (size_t)n0 * K;

  const int s0 = tid, s1 = tid + 256;
  const int r0 = s0 >> 2, c0 = ((s0 & 3) - (r0 >> 1)) & 3;
  const int r1 = s1 >> 2, c1 = ((s1 & 3) - (r1 >> 1)) & 3;
  const int pA = (quad + (l4 >> 1)) & 3;   // frag-read swizzled chunk position

  floatx4 acc[4][4] = {};

  const int nk = K >> 5;
  // prologue: stage tile 0
  gld_lds16(Ag + (size_t)r0 * lda + c0 * 8, &As[0][s0 * 8]);
  gld_lds16(Ag + (size_t)r1 * lda + c1 * 8, &As[0][s1 * 8]);
  gld_lds16(Bg + (size_t)r0 * K + c0 * 8, &Bs[0][s0 * 8]);
  gld_lds16(Bg + (size_t)r1 * K + c1 * 8, &Bs[0][s1 * 8]);
  __syncthreads();                       // drains vmcnt: tile 0 resident

  for (int kk = 0; kk < nk; ++kk) {
    const int cur = kk & 1;
    // phase 1: issue next tile's loads into the other buffer
    if (kk + 1 < nk) {
      const int k0 = (kk + 1) << 5;
      gld_lds16(Ag + (size_t)r0 * lda + k0 + c0 * 8, &As[cur ^ 1][s0 * 8]);
      gld_lds16(Ag + (size_t)r1 * lda + k0 + c1 * 8, &As[cur ^ 1][s1 * 8]);
      gld_lds16(Bg + (size_t)r0 * K + k0 + c0 * 8, &Bs[cur ^ 1][s0 * 8]);
      gld_lds16(Bg + (size_t)r1 * K + k0 + c1 * 8, &Bs[cur ^ 1][s1 * 8]);
    }
    // phase 2: compute on the current buffer
    bf16x8 af[4], bfr[4];
#pragma unroll
    for (int i = 0; i < 4; ++i)
      af[i] = *(const bf16x8*)&As[cur][(wm + i * 16 + l4) * 32 + pA * 8];
#pragma unroll
    for (int j = 0; j < 4; ++j)
      bfr[j] = *(const bf16x8*)&Bs[cur][(wn + j * 16 + l4) * 32 + pA * 8];
#pragma unroll
    for (int i = 0; i < 4; ++i)
#pragma unroll
      for (int j = 0; j < 4; ++j)
        acc[i][j] = __builtin_amdgcn_mfma_f32_16x16x32_bf16(af[i], bfr[j], acc[i][j], 0, 0, 0);
    __syncthreads();   // next tile staged + everyone done reading cur
  }

#pragma unroll
  for (int i = 0; i < 4; ++i) {
#pragma unroll
    for (int j = 0; j < 4; ++j) {
      const int col = n0 + wn + j * 16 + l4;
      float bvv = 0.f;
      if (HAS_BIAS) bvv = bias[col];
#pragma unroll
      for (int r = 0; r < 4; ++r) {
        const int row = m0 + wm + i * 16 + quad * 4 + r;
        float v = acc[i][j][r] + bvv;
        if (HAS_RES) v += b2f(res[(size_t)row * ldc + col]);
        v = fminf(fmaxf(v, -60000.f), 60000.f);  // diagnostic fingerprint; no-op on valid data
        if (OUT_F32) ((float*)Cv)[(size_t)row * ldc + col] = v;
        else         ((u16*)Cv)[(size_t)row * ldc + col] = f2b(v);
      }
    }
  }
}

// ---------------------------------------------------------------------------
// Kernel 3: attention. One block = (b, h, 128 Q rows), 4 waves, wave owns
// 32 Q rows (qi=0,1 sub-tiles of 16). KV tile = 64 rows, double-buffered
// (R4 schedule). R7 VALU cuts (R6 counters: VALUBusy 43% vs MfmaUtil 18%):
//   - exp2-fold: p = v_exp_f32(fma(s, 0.125*log2e, (1-m)*log2e)) — drops
//     __expf's hidden multiply; mask term hoisted per-iter, shared over qi.
//   - MFMA rowsum: l = P @ ones via mfma(pa, ones-frag) -> acc_l in the
//     same row layout as acc_o (cols all equal); replaces 32 VALU adds +
//     4 shfl per iter and the epilogue shuffle.
// SWAPPED QK^T (S^T in regs); P -> A-frag via cvtpk + permlane32/16 (R2).
// No max-subtraction (scores clamped, fp32-safe), single divide at end.
// Output overwrites the Q-slot of qkv (Q read to registers up front).
// ---------------------------------------------------------------------------
__global__ __launch_bounds__(256, 3) void attn_kernel(
    u16* qkv, const float* __restrict__ mask)
{
  __shared__ u16 Ks[2][64 * 64];    // 2 x 8 KB, chunk-rotation swizzle
  __shared__ u16 Vt[2][64 * 72];    // 2 x 9 KB, V transposed, +8 pad

  const int tid = threadIdx.x;
  const int lane = tid & 63, w = tid >> 6;
  const int quad = lane >> 4, l4 = lane & 15;
  const int qb = blockIdx.x;           // 0..15
  const int bh = blockIdx.y;           // 0..63
  const int b = bh >> 4, h = bh & 15;
  const int q0 = qb * 128;

  const size_t rstr = 3 * D_;
  u16* qbase = qkv + (size_t)b * S_ * rstr + h * DH_;

  // Q fragments straight to registers (B-operand: row=l4, k-chunk=quad).
  bf16x8 qfrag[2][2];
#pragma unroll
  for (int qi = 0; qi < 2; ++qi) {
    const u16* qp = qbase + (size_t)(q0 + w * 32 + qi * 16 + l4) * rstr + quad * 8;
    qfrag[qi][0] = *(const bf16x8*)(qp);
    qfrag[qi][1] = *(const bf16x8*)(qp + 32);
  }

  const u16* kbase0 = qkv + (size_t)b * S_ * rstr + D_ + h * DH_;
  const u16* vbase0 = kbase0 + D_;
  const int vs = tid & 63, vd0 = (tid >> 6) * 16;   // V reg-load: row vs, d block

  B8 ones;                                          // all-1.0 bf16 B-fragment
  ones.u[0] = ones.u[1] = ones.u[2] = ones.u[3] = 0x3f803f80u;

  floatx4 acc_o[2][4] = {};
  floatx4 acc_l[2] = {};                            // rowsum accumulators
  u16 vreg[16] __attribute__((aligned(16)));        // V[vs][vd0..vd0+16) next tile

  // --- prologue: tile 0 ---
  {
#pragma unroll
    for (int t = 0; t < 2; ++t) {      // K: 64 rows x 8 chunks = 512, 2/thread
      int sidx = tid + t * 256;
      int rr = sidx >> 3, ch = ((sidx & 7) - rr) & 7;
      gld_lds16(kbase0 + (size_t)rr * rstr + ch * 8, &Ks[0][sidx * 8]);
    }
    const u16* vp = vbase0 + (size_t)vs * rstr + vd0;
    *(uint4*)(vreg)     = *(const uint4*)(vp);
    *(uint4*)(vreg + 8) = *(const uint4*)(vp + 8);
  }
  __syncthreads();                     // drains vmcnt: K0 in LDS, V0 in regs
#pragma unroll
  for (int d = 0; d < 16; ++d) Vt[0][(vd0 + d) * 72 + vs] = vreg[d];
  __syncthreads();                     // Vt0 visible to all waves

  int cur = 0;
  for (int j = 0; j < 32; ++j) {
    // phase 1: issue next tile's loads (V regs first so its vmcnt wait
    // doesn't drain the K gld_lds queue)
    if (j < 31) {
      const u16* vp = vbase0 + ((size_t)(j + 1) * 64 + vs) * rstr + vd0;
      *(uint4*)(vreg)     = *(const uint4*)(vp);
      *(uint4*)(vreg + 8) = *(const uint4*)(vp + 8);
      const u16* kb = kbase0 + (size_t)(j + 1) * 64 * rstr;
#pragma unroll
      for (int t = 0; t < 2; ++t) {
        int sidx = tid + t * 256;
        int rr = sidx >> 3, ch = ((sidx & 7) - rr) & 7;
        gld_lds16(kb + (size_t)rr * rstr + ch * 8, &Ks[cur ^ 1][sidx * 8]);
      }
    }

    // phase 2: S^T on Ks[cur]: accs[qi][tj][r] = S[k=tj*16+quad*4+r][q=w*32+qi*16+l4]
    // kf fragments shared across qi — 8 ds_reads feed 16 MFMA.
    floatx4 accs[2][4] = {};
#pragma unroll
    for (int kc = 0; kc < 2; ++kc)
#pragma unroll
      for (int tj = 0; tj < 4; ++tj) {
        const int rk = tj * 16 + l4;
        bf16x8 kf = *(const bf16x8*)&Ks[cur][rk * 64 + (((kc * 4 + quad) + rk) & 7) * 8];
        accs[0][tj] = __builtin_amdgcn_mfma_f32_16x16x32_bf16(kf, qfrag[0][kc], accs[0][tj], 0, 0, 0);
        accs[1][tj] = __builtin_amdgcn_mfma_f32_16x16x32_bf16(kf, qfrag[1][kc], accs[1][tj], 0, 0, 0);
      }

    // softmax: p = 2^(s*0.125*log2e + (1-m)*log2e), clamped. mterm shared
    // across qi; rowsum deferred to the MFMA-ones pass below.
    const float* mrow = mask + (size_t)b * S_ + j * 64 + quad * 4;
    float mterm[4][4];
#pragma unroll
    for (int tj = 0; tj < 4; ++tj) {
      float4 mv = *(const float4*)(mrow + tj * 16);
      mterm[tj][0] = fmaf(mv.x, -1.44269504f, 1.44269504f);
      mterm[tj][1] = fmaf(mv.y, -1.44269504f, 1.44269504f);
      mterm[tj][2] = fmaf(mv.z, -1.44269504f, 1.44269504f);
      mterm[tj][3] = fmaf(mv.w, -1.44269504f, 1.44269504f);
    }
    unsigned pk[2][4][2];
#pragma unroll
    for (int qi = 0; qi < 2; ++qi) {
#pragma unroll
      for (int tj = 0; tj < 4; ++tj) {
        float p0 = fexp2(fminf(fmaf(accs[qi][tj][0], 0.18033688f, mterm[tj][0]), 43.3f));
        float p1 = fexp2(fminf(fmaf(accs[qi][tj][1], 0.18033688f, mterm[tj][1]), 43.3f));
        float p2 = fexp2(fminf(fmaf(accs[qi][tj][2], 0.18033688f, mterm[tj][2]), 43.3f));
        float p3 = fexp2(fminf(fmaf(accs[qi][tj][3], 0.18033688f, mterm[tj][3]), 43.3f));
        pk[qi][tj][0] = cvtpk(p0, p1);
        pk[qi][tj][1] = cvtpk(p2, p3);
      }
    }

    // O += P V on Vt[cur]; l += P @ ones. bfr shared across qi.
#pragma unroll
    for (int kc = 0; kc < 2; ++kc) {
      bf16x8 bfr[4];
#pragma unroll
      for (int tn = 0; tn < 4; ++tn)
        bfr[tn] = *(const bf16x8*)&Vt[cur][(tn * 16 + l4) * 72 + kc * 32 + quad * 8];
#pragma unroll
      for (int qi = 0; qi < 2; ++qi) {
        unsigned x0 = pk[qi][2 * kc][0], x1 = pk[qi][2 * kc + 1][0];
        unsigned y0 = pk[qi][2 * kc][1], y1 = pk[qi][2 * kc + 1][1];
        PL32(x0, x1); PL32(y0, y1);   // reg-pair bit <-> lane-bit5
        PL16(x0, x1); PL16(y0, y1);   // reg-pair bit <-> lane-bit4
        B8 pa; pa.u[0] = x0; pa.u[1] = y0; pa.u[2] = x1; pa.u[3] = y1;
        __builtin_amdgcn_s_setprio(1);
#pragma unroll
        for (int tn = 0; tn < 4; ++tn)
          acc_o[qi][tn] = __builtin_amdgcn_mfma_f32_16x16x32_bf16(pa.v, bfr[tn], acc_o[qi][tn], 0, 0, 0);
        acc_l[qi] = __builtin_amdgcn_mfma_f32_16x16x32_bf16(pa.v, ones.v, acc_l[qi], 0, 0, 0);
        __builtin_amdgcn_s_setprio(0);
      }
    }

    // phase 3: write next tile's Vt (prev-iter barrier guarantees Vt[cur^1]
    // free; vreg's vmcnt wait lands here — after a full compute phase)
    if (j < 31) {
#pragma unroll
      for (int d = 0; d < 16; ++d) Vt[cur ^ 1][(vd0 + d) * 72 + vs] = vreg[d];
    }

    __syncthreads();   // drains K gld_lds (issued pre-compute) + Vt writes
    cur ^= 1;
  }

  // epilogue: acc_l[qi][r] = rowsum for row quad*4+r (all cols equal)
#pragma unroll
  for (int qi = 0; qi < 2; ++qi) {
    float inv[4];
#pragma unroll
    for (int r = 0; r < 4; ++r) inv[r] = 1.0f / acc_l[qi][r];
#pragma unroll
    for (int tn = 0; tn < 4; ++tn) {
#pragma unroll
      for (int r = 0; r < 4; ++r) {
        const int row = q0 + w * 32 + qi * 16 + quad * 4 + r;
        const int col = h * DH_ + tn * 16 + l4;
        qkv[((size_t)b * S_ + row) * rstr + col] = f2b(acc_o[qi][tn][r] * inv[r]);
      }
    }
  }
}

// ---------------------------------------------------------------------------
extern "C" void kernel_launch(void* const* d_in, const int* in_sizes, int n_in,
                              void* d_out, int out_size, void* d_ws, size_t ws_size,
                              hipStream_t stream) {
  const float* x    = (const float*)d_in[0];
  const float* mask = (const float*)d_in[1];
  const float* pos  = (const float*)d_in[2];
  const float* gam  = (const float*)d_in[3];
  const float* bet  = (const float*)d_in[4];
  const float* wqkv = (const float*)d_in[5];
  const float* bqkv = (const float*)d_in[6];
  const float* wo   = (const float*)d_in[7];
  const float* bo   = (const float*)d_in[8];
  const float* wt   = (const float*)d_in[9];
  const float* bt   = (const float*)d_in[10];
  float* out = (float*)d_out;

  // workspace: exactly 64 MiB
  char* ws = (char*)d_ws;
  u16* qkvb = (u16*)(ws);                        // 8192 x 3072 bf16 = 50.33 MB
  u16* xp   = (u16*)(ws + (size_t)50331648);     // 8192 x 1024 bf16 = 16.78 MB

  // weight scratch in d_out (dead until kernel 5; 8.4 MB of 33.5 MB):
  u16* wqkv_b = (u16*)d_out;                              // 3072x1024 bf16
  u16* wo_b   = (u16*)((char*)d_out + (size_t)6291456);   // 1024x1024 bf16
  // wt converted into qkvb region after kernel 4 (qkvb dead by then)
  u16* wt_b   = qkvb;

  const int nqkv = 3 * D_ * D_;   // 3,145,728
  const int nd   = D_ * D_;       // 1,048,576

  // 0. convert weights used before kernel 5
  cvt_f32_bf16<<<nqkv / 1024, 256, 0, stream>>>(wqkv, wqkv_b, nqkv);
  cvt_f32_bf16<<<nd   / 1024, 256, 0, stream>>>(wo,   wo_b,   nd);
  // 1. layernorm + pos emb -> xp (bf16)
  ln_pos_kernel<<<B_ * S_, 256, 0, stream>>>(x, pos, gam, bet, xp);
  // 2. qkv = xp @ Wqkv^T + b   [8192,3072] bf16
  gemm_bt<1, 0, 0><<<dim3(3 * D_ / 128, B_ * S_ / 128), 256, 0, stream>>>(
      xp, wqkv_b, bqkv, nullptr, qkvb, B_ * S_, 3 * D_, D_, D_, 3 * D_);
  // 3. attention; output overwrites the Q-slot of qkvb (stride 3072)
  attn_kernel<<<dim3(S_ / 128, B_ * H_), 256, 0, stream>>>(qkvb, mask);
  // 4. xp = attn_out @ Wo^T + bo + xp   (A = Q-slot of qkvb, lda=3072; in-place)
  gemm_bt<1, 1, 0><<<dim3(D_ / 128, B_ * S_ / 128), 256, 0, stream>>>(
      qkvb, wo_b, bo, xp, xp, B_ * S_, D_, D_, 3 * D_, D_);
  // 4b. convert Wt into (now dead) qkvb region
  cvt_f32_bf16<<<nd / 1024, 256, 0, stream>>>(wt, wt_b, nd);
  // 5. out = xp @ Wt^T + bt  -> fp32 d_out
  gemm_bt<1, 0, 1><<<dim3(D_ / 128, B_ * S_ / 128), 256, 0, stream>>>(
      xp, wt_b, bt, nullptr, out, B_ * S_, D_, D_, D_, D_);
}